// Round 9
// baseline (214.767 us; speedup 1.0000x reference)
//
#include <hip/hip_runtime.h>
#include <hip/hip_fp16.h>

#define N_NODES 10000
#define EDGES   160000
#define BATCH   8
#define TT      12
#define HID     64
#define CAP     64       // fixed edge-slot capacity per node (avg deg 16, P(deg>64) ~ 0)

typedef _Float16 f16x8 __attribute__((ext_vector_type(8)));
typedef _Float16 f16x4 __attribute__((ext_vector_type(4)));
typedef float    f32x4 __attribute__((ext_vector_type(4)));

// permutation of k within a 32-k group so one b128 (8 halves) = one MFMA fragment:
// fragment wants k = {4g..4g+3, 16+4g..16+4g+3} at lane group g -> store k at
// pos = 8*g + 4*h + j  (g=(k>>2)&3, h=k>>4, j=k&3).  HW-verified (rounds 6-7 passed).
__host__ __device__ __forceinline__ int kperm(int k31) {
  return (((k31 >> 2) & 3) << 3) + ((k31 >> 4) << 2) + (k31 & 3);
}

// ---------------- CSR build (fixed-capacity, no scan) ----------------

__global__ __launch_bounds__(256) void k_fillfix(const int* __restrict__ ei,
                                                 const float* __restrict__ ew,
                                                 int* __restrict__ cur,
                                                 int* __restrict__ csrc,
                                                 float* __restrict__ cnorm) {
  int g = blockIdx.x * 256 + threadIdx.x;
  if (g < EDGES) {
    int s = ei[g], d = ei[EDGES + g];
    int slot = atomicAdd(&cur[d], 1);
    csrc[d * CAP + slot]  = s;
    cnorm[d * CAP + slot] = ew[g];
  }
}

__global__ __launch_bounds__(256) void k_degpad(const int* __restrict__ cur,
                                                int* __restrict__ csrc,
                                                float* __restrict__ cnorm,
                                                float* __restrict__ dinv,
                                                int* __restrict__ mcnt) {
  int n = blockIdx.x * 4 + (threadIdx.x >> 6);
  int lane = threadIdx.x & 63;
  int cnt = cur[n];
  int m = (cnt + 7) & ~7;
  int base = n * CAP;
  if (lane >= cnt && lane < m) { csrc[base + lane] = 0; cnorm[base + lane] = 0.0f; }
  float s = (lane < cnt) ? cnorm[base + lane] : 0.0f;
  #pragma unroll
  for (int off = 32; off > 0; off >>= 1) s += __shfl_xor(s, off, 64);
  if (lane == 0) {
    dinv[n] = 1.0f / sqrtf(s + 1.0f);
    mcnt[n] = m;
  }
}

// merged: blocks 0..2499 = wnorm; blocks 2500.. = weight pack into fp16,
// TRANSPOSED [col][k] with per-32-group kperm (MFMA B-fragment = one b128):
//  p1ct ushort[128][192], p2ct ushort[64][128], W2t ushort[64][64], pb1 float[128]
__global__ __launch_bounds__(256) void k_wnormpack(const int* __restrict__ cur,
                                                   const int* __restrict__ csrc,
                                                   const float* __restrict__ dinv,
                                                   float* __restrict__ cnorm,
                                                   const float* __restrict__ tc1w,
                                                   const float* __restrict__ tc2w,
                                                   const float* __restrict__ tc1b,
                                                   const float* __restrict__ W2,
                                                   ushort* __restrict__ p1ct,
                                                   ushort* __restrict__ p2ct,
                                                   ushort* __restrict__ W2t,
                                                   float* __restrict__ pb1) {
  if (blockIdx.x < 2500) {
    int n = blockIdx.x * 4 + (threadIdx.x >> 6);
    int lane = threadIdx.x & 63;
    int cnt = cur[n];
    int m = (cnt + 7) & ~7;
    if (lane < m) {
      int idx = n * CAP + lane;
      cnorm[idx] = cnorm[idx] * dinv[csrc[idx]] * dinv[n];
    }
  } else {
    int g = (blockIdx.x - 2500) * 256 + threadIdx.x;
    if (g < 24576) {                       // p1ct: k = t3*64+i, col = t'*64+o
      int kk = g >> 7, col = g & 127;
      int t3 = kk >> 6, i = kk & 63;
      int half = col >> 6, o = col & 63;
      float v;
      if (half == 0) v = tc1w[o * 192 + i * 3 + t3];
      else           v = (t3 == 0) ? 0.0f : tc1w[o * 192 + i * 3 + (t3 - 1)];
      p1ct[col * 192 + (kk >> 5) * 32 + kperm(kk & 31)] = __half_as_ushort(__float2half_rn(v));
    } else if (g < 32768) {                // p2ct: k = t'*64+i, col = o
      int r = g - 24576;
      int kk = r >> 6, o = r & 63;
      int gk = kk >> 6, i = kk & 63;
      float v = tc2w[o * 192 + i * 3 + gk];
      p2ct[o * 128 + (kk >> 5) * 32 + kperm(kk & 31)] = __half_as_ushort(__float2half_rn(v));
    } else if (g < 36864) {                // W2t: k = c_in, col = c_out
      int r = g - 32768;
      int kk = r >> 6, c = r & 63;
      float v = W2[kk * 64 + c];
      W2t[c * 64 + (kk >> 5) * 32 + kperm(kk & 31)] = __half_as_ushort(__float2half_rn(v));
    } else if (g < 36992) {
      int r = g - 36864;
      pb1[r] = tc1b[r & 63];
    }
  }
}

// ---------------- GCN layer 1: fused agg(X) @ W1 + b1, relu ----------------
// h1 FP16 (3.84MB/batch slab -> L2-resident gather). Layout (ushort units):
// [0..128) = interleaved (t0[c],t1[c]) half2 at 2c; [128..192) = t2[c].

__global__ __launch_bounds__(256) void k_aggg1(const float* __restrict__ X,
                                               const float* __restrict__ dinv,
                                               const int* __restrict__ mcnt,
                                               const int* __restrict__ csrc,
                                               const float* __restrict__ cnorm,
                                               const float* __restrict__ W1,
                                               const float* __restrict__ b1,
                                               ushort* __restrict__ h1) {
  int b = blockIdx.x & 7;                    // batch -> XCD affinity
  int grp = blockIdx.x >> 3;                 // 0..2499
  int n = grp * 4 + (threadIdx.x >> 6);
  int lane = threadIdx.x & 63;
  const float2* x0 = (const float2*)(X + (size_t)(b * TT + 9)  * N_NODES * 2);
  const float2* x1 = (const float2*)(X + (size_t)(b * TT + 10) * N_NODES * 2);
  const float2* x2 = (const float2*)(X + (size_t)(b * TT + 11) * N_NODES * 2);
  float a0x = 0.f, a0y = 0.f, a1x = 0.f, a1y = 0.f, a2x = 0.f, a2y = 0.f;
  int m = mcnt[n];
  if (lane < m) {
    int idx = n * CAP + lane;
    float w = cnorm[idx];
    int s = csrc[idx];
    float2 s0 = x0[s], s1 = x1[s], s2v = x2[s];
    a0x = w * s0.x;  a0y = w * s0.y;
    a1x = w * s1.x;  a1y = w * s1.y;
    a2x = w * s2v.x; a2y = w * s2v.y;
  }
  if (lane == 0) {  // self-loop term
    float di = dinv[n];
    float sd = di * di;
    float2 v0 = x0[n], v1 = x1[n], v2 = x2[n];
    a0x += sd * v0.x; a0y += sd * v0.y;
    a1x += sd * v1.x; a1y += sd * v1.y;
    a2x += sd * v2.x; a2y += sd * v2.y;
  }
  #pragma unroll
  for (int off = 32; off > 0; off >>= 1) {
    a0x += __shfl_xor(a0x, off, 64);
    a0y += __shfl_xor(a0y, off, 64);
    a1x += __shfl_xor(a1x, off, 64);
    a1y += __shfl_xor(a1y, off, 64);
    a2x += __shfl_xor(a2x, off, 64);
    a2y += __shfl_xor(a2y, off, 64);
  }
  int c = lane;
  float w0 = W1[c], w1 = W1[64 + c], bc = b1[c];
  float r0 = fmaxf(a0x * w0 + a0y * w1 + bc, 0.0f);
  float r1 = fmaxf(a1x * w0 + a1y * w1 + bc, 0.0f);
  float r2 = fmaxf(a2x * w0 + a2y * w1 + bc, 0.0f);
  ushort* row = h1 + ((size_t)(b * N_NODES + n)) * 192;
  *(__half2*)(row + 2 * c)  = __floats2half2_rn(r0, r1);
  *(__half*)(row + 128 + c) = __float2half_rn(r2);
}

// ---------------- v7: gather FUSED into the epilogue (no ah16 round-trip) ----------------
// Grid = 8 x 313: block -> b = blockIdx&7 (batch -> XCD affinity; h1 slab L2-resident,
// still warm from k_aggg1 on the same XCD), grp = blockIdx>>3, nodes n0=32*grp..+31
// (tail block guards n >= 10000; garbage rows are confined — all GEMM phases are
// row-independent — and output stores are guarded).
// Phase 0: wave w gathers nodes j = 8w..8w+7 (round-7 k_agg3m16 inner loop verbatim,
// fp32 accum) and writes fp16 straight into the swizzled As tile -> bitwise-identical
// results to round 7, minus 61MB of ah16 HBM traffic and one kernel launch.
// Phases 1-3 = FROZEN v6 structure. LDS 40,960B -> 4 blocks/CU (16 waves/CU).
__global__ __launch_bounds__(256, 4) void k_gfused(const ushort* __restrict__ h1,
                                                   const float* __restrict__ dinv,
                                                   const int* __restrict__ mcnt,
                                                   const int* __restrict__ csrc,
                                                   const float* __restrict__ cnorm,
                                                   const ushort* __restrict__ W2t,
                                                   const float* __restrict__ b2,
                                                   const ushort* __restrict__ p1ct,
                                                   const float* __restrict__ pb1,
                                                   const ushort* __restrict__ p2ct,
                                                   const float* __restrict__ tc2b,
                                                   const float* __restrict__ ow,
                                                   const float* __restrict__ obp,
                                                   float* __restrict__ out) {
  __shared__ __align__(16) ushort smem[20480];     // 40,960 B -> 4 blocks/CU
  ushort* spL = smem;                              // [32][192]
  ushort* As  = smem + 6144;                       // [96][64]   (phase 0/1)
  ushort* W2s = smem + 12288;                      // [64][64]   (phase 1)
  ushort* Wc  = smem + 6144;                       // [128][64] chunk / [64][128] p2c
  ushort* t1L = smem + 16384;                      // [32][128]
  float*  red = (float*)smem;                      // [4][32] floats; overlays dead spL

  int tid = threadIdx.x;
  int lane = tid & 63, w = tid >> 6;
  int l15 = lane & 15, g = lane >> 4;
  int b   = blockIdx.x & 7;                        // batch -> XCD affinity
  int grp = blockIdx.x >> 3;                       // 0..312
  int n0  = grp * 32;
  const ushort* hb = h1 + (size_t)b * N_NODES * 192;

  // ---- stage W2s early (independent of the gather)
  #pragma unroll
  for (int r = 0; r < 2; r++) {
    int u = r * 256 + tid;                         // 512 x 8 halves
    int cl = u >> 3, hu = u & 7;
    *(uint4*)&W2s[cl * 64 + ((hu * 8) ^ ((cl & 7) << 3))] =
        *(const uint4*)&W2t[cl * 64 + hu * 8];
  }

  // ---- phase 0: gather-aggregate 8 nodes per wave straight into As (fp32 accum)
  {
    int c = lane;
    int ohc = ((c >> 5) << 5) + kperm(c & 31);     // kperm'd within-row position
    for (int jj = 0; jj < 8; jj++) {
      int j = w * 8 + jj;
      int n = n0 + j;
      float acc0 = 0.f, acc1 = 0.f, acc2 = 0.f;
      if (n < N_NODES) {
        int m = mcnt[n];                           // <= 64, multiple of 8
        int idx = n * CAP + c;
        int ic = (c < m) ? idx : n * CAP;
        int sv = csrc[ic] * 192;                   // ushort offset of source row
        float wf = (c < m) ? cnorm[idx] : 0.0f;
        int wb = __float_as_int(wf);
        for (int e = 0; e < m; e += 8) {
          #pragma unroll
          for (int u = 0; u < 8; u++) {
            int   off = __builtin_amdgcn_readlane(sv, e + u);
            float ww  = __int_as_float(__builtin_amdgcn_readlane(wb, e + u));
            const ushort* p = hb + off;
            float2 f01 = __half22float2(*(const __half2*)(p + 2 * c));
            float  t2v = __half2float(*(const __half*)(p + 128 + c));
            acc0 += ww * f01.x;
            acc1 += ww * f01.y;
            acc2 += ww * t2v;
          }
        }
        float di = dinv[n];
        float s2 = di * di;
        const ushort* sr = hb + (size_t)n * 192;
        float2 fs = __half22float2(*(const __half2*)(sr + 2 * c));
        float  fst = __half2float(*(const __half*)(sr + 128 + c));
        acc0 += s2 * fs.x;
        acc1 += s2 * fs.y;
        acc2 += s2 * fst;
      }
      int m0 = 3 * j;                              // As rows m0..m0+2 (t3 = 0,1,2)
      As[(m0 + 0) * 64 + (ohc ^ (((m0 + 0) & 7) << 3))] = __half_as_ushort(__float2half_rn(acc0));
      As[(m0 + 1) * 64 + (ohc ^ (((m0 + 1) & 7) << 3))] = __half_as_ushort(__float2half_rn(acc1));
      As[(m0 + 2) * 64 + (ohc ^ (((m0 + 2) & 7) << 3))] = __half_as_ushort(__float2half_rn(acc2));
    }
  }
  __syncthreads();

  // ---- phase 1: sp = relu(As[96x64] @ W2[64x64] + b2); wave w = cols 16w..16w+15
  {
    int col = w * 16 + l15;
    float bias = b2[col];
    f32x4 acc[6];
    #pragma unroll
    for (int i = 0; i < 6; i++) acc[i] = (f32x4){0.f, 0.f, 0.f, 0.f};
    #pragma unroll
    for (int s = 0; s < 2; s++) {
      int oh = s * 32 + 8 * g;
      f16x8 bf = *(const f16x8*)&W2s[col * 64 + (oh ^ ((col & 7) << 3))];
      #pragma unroll
      for (int mi = 0; mi < 6; mi++) {
        int row = mi * 16 + l15;
        f16x8 af = *(const f16x8*)&As[row * 64 + (oh ^ ((row & 7) << 3))];
        acc[mi] = __builtin_amdgcn_mfma_f32_16x16x32_f16(af, bf, acc[mi], 0, 0, 0);
      }
    }
    // epilogue: D row m=(3n+t3) col c -> spL A-layout row n, k = t3*64+c (perm+swz)
    #pragma unroll
    for (int mi = 0; mi < 6; mi++) {
      #pragma unroll
      for (int r = 0; r < 4; r++) {
        int m = mi * 16 + 4 * g + r;
        int n = m / 3, t3 = m - 3 * n;
        float v = fmaxf(acc[mi][r] + bias, 0.0f);
        int k = t3 * 64 + col;
        int oh = (k >> 5) * 32 + kperm(k & 31);
        *(_Float16*)&spL[n * 192 + (oh ^ ((n & 7) << 3))] = (_Float16)v;
      }
    }
  }
  __syncthreads();                                 // As/W2s dead; spL ready

  // ---- phase 2: t1 = relu(spL[32x192] @ p1c[192x128] + pb1); 3 K-chunks of 64
  f32x4 acc2[2][2];
  #pragma unroll
  for (int i = 0; i < 2; i++)
    #pragma unroll
    for (int j = 0; j < 2; j++) acc2[i][j] = (f32x4){0.f, 0.f, 0.f, 0.f};
  int c0 = 32 * w + l15, c1 = c0 + 16;             // wave w cols {32w..+15, 32w+16..+31}
  for (int cc = 0; cc < 3; cc++) {
    #pragma unroll
    for (int r = 0; r < 4; r++) {                  // stage [128 col][64 k] chunk
      int u = r * 256 + tid;
      int cl = u >> 3, hu = u & 7;
      *(uint4*)&Wc[cl * 64 + ((hu * 8) ^ ((cl & 7) << 3))] =
          *(const uint4*)&p1ct[cl * 192 + cc * 64 + hu * 8];
    }
    __syncthreads();
    #pragma unroll
    for (int ks = 0; ks < 2; ks++) {
      int ohB = ks * 32 + 8 * g;
      f16x8 bf0 = *(const f16x8*)&Wc[c0 * 64 + (ohB ^ ((c0 & 7) << 3))];
      f16x8 bf1 = *(const f16x8*)&Wc[c1 * 64 + (ohB ^ ((c1 & 7) << 3))];
      int ohA = (cc * 2 + ks) * 32 + 8 * g;
      #pragma unroll
      for (int mi = 0; mi < 2; mi++) {
        int row = mi * 16 + l15;
        f16x8 af = *(const f16x8*)&spL[row * 192 + (ohA ^ ((row & 7) << 3))];
        acc2[mi][0] = __builtin_amdgcn_mfma_f32_16x16x32_f16(af, bf0, acc2[mi][0], 0, 0, 0);
        acc2[mi][1] = __builtin_amdgcn_mfma_f32_16x16x32_f16(af, bf1, acc2[mi][1], 0, 0, 0);
      }
    }
    __syncthreads();
  }
  // epilogue: t1L A-layout row n, k = col (perm+swz)
  {
    float bz0 = pb1[c0], bz1 = pb1[c1];
    int oh0 = (c0 >> 5) * 32 + kperm(c0 & 31);
    int oh1 = (c1 >> 5) * 32 + kperm(c1 & 31);
    #pragma unroll
    for (int mi = 0; mi < 2; mi++) {
      #pragma unroll
      for (int r = 0; r < 4; r++) {
        int n = mi * 16 + 4 * g + r;
        float v0 = fmaxf(acc2[mi][0][r] + bz0, 0.0f);
        float v1 = fmaxf(acc2[mi][1][r] + bz1, 0.0f);
        *(_Float16*)&t1L[n * 128 + (oh0 ^ ((n & 7) << 3))] = (_Float16)v0;
        *(_Float16*)&t1L[n * 128 + (oh1 ^ ((n & 7) << 3))] = (_Float16)v1;
      }
    }
  }
  // ---- stage p2cs [64 col][128 k] into Wc (t1L and Wc disjoint; one barrier)
  #pragma unroll
  for (int r = 0; r < 4; r++) {
    int u = r * 256 + tid;                         // 1024 x 8 halves
    int cl = u >> 4, hu = u & 15;
    *(uint4*)&Wc[cl * 128 + ((hu * 8) ^ ((cl & 7) << 3))] =
        *(const uint4*)&p2ct[cl * 128 + hu * 8];
  }
  __syncthreads();

  // ---- phase 3: last = relu(t1L[32x128] @ p2c[128x64] + tc2b); dot with ow
  {
    int col = 16 * w + l15;
    f32x4 acc3[2];
    acc3[0] = (f32x4){0.f, 0.f, 0.f, 0.f};
    acc3[1] = (f32x4){0.f, 0.f, 0.f, 0.f};
    #pragma unroll
    for (int s = 0; s < 4; s++) {
      int oh = s * 32 + 8 * g;
      f16x8 bf = *(const f16x8*)&Wc[col * 128 + (oh ^ ((col & 7) << 3))];
      #pragma unroll
      for (int mi = 0; mi < 2; mi++) {
        int row = mi * 16 + l15;
        f16x8 af = *(const f16x8*)&t1L[row * 128 + (oh ^ ((row & 7) << 3))];
        acc3[mi] = __builtin_amdgcn_mfma_f32_16x16x32_f16(af, bf, acc3[mi], 0, 0, 0);
      }
    }
    float tb = tc2b[col], o4 = ow[col];
    float s4[2][4];
    #pragma unroll
    for (int mi = 0; mi < 2; mi++)
      #pragma unroll
      for (int r = 0; r < 4; r++)
        s4[mi][r] = fmaxf(acc3[mi][r] + tb, 0.0f) * o4;
    #pragma unroll
    for (int off = 1; off <= 8; off <<= 1) {
      #pragma unroll
      for (int mi = 0; mi < 2; mi++)
        #pragma unroll
        for (int r = 0; r < 4; r++)
          s4[mi][r] += __shfl_xor(s4[mi][r], off, 64);
    }
    if (l15 == 0) {
      #pragma unroll
      for (int mi = 0; mi < 2; mi++) {
        float4 o;
        o.x = s4[mi][0]; o.y = s4[mi][1]; o.z = s4[mi][2]; o.w = s4[mi][3];
        *(float4*)&red[w * 32 + mi * 16 + 4 * g] = o;
      }
    }
  }
  __syncthreads();
  if (tid < 32) {
    int n = n0 + tid;
    if (n < N_NODES) {
      float v = red[tid] + red[32 + tid] + red[64 + tid] + red[96 + tid] + obp[0];
      out[(size_t)b * N_NODES + n] = v;
    }
  }
}

// ---------------- launch ----------------

extern "C" void kernel_launch(void* const* d_in, const int* in_sizes, int n_in,
                              void* d_out, int out_size, void* d_ws, size_t ws_size,
                              hipStream_t stream) {
  const float* X    = (const float*)d_in[0];
  const int*   EI   = (const int*)  d_in[1];
  const float* EW   = (const float*)d_in[2];
  const float* W1   = (const float*)d_in[3];
  const float* B1   = (const float*)d_in[4];
  const float* W2   = (const float*)d_in[5];
  const float* B2   = (const float*)d_in[6];
  const float* TC1W = (const float*)d_in[7];
  const float* TC1B = (const float*)d_in[8];
  const float* TC2W = (const float*)d_in[9];
  const float* TC2B = (const float*)d_in[10];
  const float* OW   = (const float*)d_in[11];
  const float* OB   = (const float*)d_in[12];
  float* out = (float*)d_out;

  char* base = (char*)d_ws;
  size_t off = 0;
  auto alloc = [&](size_t bytes) -> char* {
    char* p = base + off;
    off += (bytes + 255) & ~(size_t)255;
    return p;
  };
  float*  dinv  = (float*) alloc(N_NODES * 4);
  int*    cur   = (int*)   alloc(N_NODES * 4);
  int*    mcnt  = (int*)   alloc(N_NODES * 4);
  int*    csrc  = (int*)   alloc((size_t)N_NODES * CAP * 4);
  float*  cnorm = (float*) alloc((size_t)N_NODES * CAP * 4);
  ushort* p1ct  = (ushort*)alloc(128 * 192 * 2);
  ushort* p2ct  = (ushort*)alloc(64 * 128 * 2);
  ushort* W2t   = (ushort*)alloc(64 * 64 * 2);
  float*  pb1   = (float*) alloc(128 * 4);
  const size_t BIG = (size_t)80000 * 192;
  ushort* h1 = (ushort*)alloc(BIG * 2);    // fp16 h1: 3.84 MB/batch slab (L2-resident)

  hipMemsetAsync(cur, 0, N_NODES * 4, stream);
  k_fillfix<<<625, 256, 0, stream>>>(EI, EW, cur, csrc, cnorm);
  k_degpad<<<2500, 256, 0, stream>>>(cur, csrc, cnorm, dinv, mcnt);
  // wnorm (blocks 0..2499) + fp16 transposed/permuted weight pack (blocks 2500..2644)
  k_wnormpack<<<2645, 256, 0, stream>>>(cur, csrc, dinv, cnorm, TC1W, TC2W, TC1B, W2,
                                        p1ct, p2ct, W2t, pb1);

  // layer 1 (agg + W1 + relu), t=9..11 fused; h1 fp16 packed (t0,t1 half2 | t2)
  k_aggg1<<<20000, 256, 0, stream>>>(X, dinv, mcnt, csrc, cnorm, W1, B1, h1);
  // v7: layer-2 gather fused into the MFMA epilogue; batch->XCD affine grid 8x313
  k_gfused<<<2504, 256, 0, stream>>>(h1, dinv, mcnt, csrc, cnorm,
                                     W2t, B2, p1ct, pb1, p2ct, TC2B, OW, OB, out);
}

// Round 10
// 192.679 us; speedup vs baseline: 1.1146x; 1.1146x over previous
//
#include <hip/hip_runtime.h>
#include <hip/hip_fp16.h>

#define N_NODES 10000
#define EDGES   160000
#define BATCH   8
#define TT      12
#define HID     64
#define CAP     64       // fixed edge-slot capacity per node (avg deg 16, P(deg>64) ~ 0)

typedef _Float16 f16x8 __attribute__((ext_vector_type(8)));
typedef _Float16 f16x4 __attribute__((ext_vector_type(4)));
typedef float    f32x4 __attribute__((ext_vector_type(4)));

// permutation of k within a 32-k group so one b128 (8 halves) = one MFMA fragment:
// fragment wants k = {4g..4g+3, 16+4g..16+4g+3} at lane group g -> store k at
// pos = 8*g + 4*h + j  (g=(k>>2)&3, h=k>>4, j=k&3).  HW-verified (rounds 6-7 passed).
__host__ __device__ __forceinline__ int kperm(int k31) {
  return (((k31 >> 2) & 3) << 3) + ((k31 >> 4) << 2) + (k31 & 3);
}

// ---------------- CSR build (fixed-capacity, no scan) ----------------

__global__ __launch_bounds__(256) void k_fillfix(const int* __restrict__ ei,
                                                 const float* __restrict__ ew,
                                                 int* __restrict__ cur,
                                                 int* __restrict__ csrc,
                                                 float* __restrict__ cnorm) {
  int g = blockIdx.x * 256 + threadIdx.x;
  if (g < EDGES) {
    int s = ei[g], d = ei[EDGES + g];
    int slot = atomicAdd(&cur[d], 1);
    csrc[d * CAP + slot]  = s;
    cnorm[d * CAP + slot] = ew[g];
  }
}

__global__ __launch_bounds__(256) void k_degpad(const int* __restrict__ cur,
                                                int* __restrict__ csrc,
                                                float* __restrict__ cnorm,
                                                float* __restrict__ dinv,
                                                int* __restrict__ mcnt) {
  int n = blockIdx.x * 4 + (threadIdx.x >> 6);
  int lane = threadIdx.x & 63;
  int cnt = cur[n];
  int m = (cnt + 7) & ~7;
  int base = n * CAP;
  if (lane >= cnt && lane < m) { csrc[base + lane] = 0; cnorm[base + lane] = 0.0f; }
  float s = (lane < cnt) ? cnorm[base + lane] : 0.0f;
  #pragma unroll
  for (int off = 32; off > 0; off >>= 1) s += __shfl_xor(s, off, 64);
  if (lane == 0) {
    dinv[n] = 1.0f / sqrtf(s + 1.0f);
    mcnt[n] = m;
  }
}

// merged: blocks 0..2499 = wnorm; blocks 2500.. = weight pack into fp16,
// TRANSPOSED [col][k] with per-32-group kperm (MFMA B-fragment = one b128):
//  p1ct ushort[128][192], p2ct ushort[64][128], W2t ushort[64][64], pb1 float[128]
__global__ __launch_bounds__(256) void k_wnormpack(const int* __restrict__ cur,
                                                   const int* __restrict__ csrc,
                                                   const float* __restrict__ dinv,
                                                   float* __restrict__ cnorm,
                                                   const float* __restrict__ tc1w,
                                                   const float* __restrict__ tc2w,
                                                   const float* __restrict__ tc1b,
                                                   const float* __restrict__ W2,
                                                   ushort* __restrict__ p1ct,
                                                   ushort* __restrict__ p2ct,
                                                   ushort* __restrict__ W2t,
                                                   float* __restrict__ pb1) {
  if (blockIdx.x < 2500) {
    int n = blockIdx.x * 4 + (threadIdx.x >> 6);
    int lane = threadIdx.x & 63;
    int cnt = cur[n];
    int m = (cnt + 7) & ~7;
    if (lane < m) {
      int idx = n * CAP + lane;
      cnorm[idx] = cnorm[idx] * dinv[csrc[idx]] * dinv[n];
    }
  } else {
    int g = (blockIdx.x - 2500) * 256 + threadIdx.x;
    if (g < 24576) {                       // p1ct: k = t3*64+i, col = t'*64+o
      int kk = g >> 7, col = g & 127;
      int t3 = kk >> 6, i = kk & 63;
      int half = col >> 6, o = col & 63;
      float v;
      if (half == 0) v = tc1w[o * 192 + i * 3 + t3];
      else           v = (t3 == 0) ? 0.0f : tc1w[o * 192 + i * 3 + (t3 - 1)];
      p1ct[col * 192 + (kk >> 5) * 32 + kperm(kk & 31)] = __half_as_ushort(__float2half_rn(v));
    } else if (g < 32768) {                // p2ct: k = t'*64+i, col = o
      int r = g - 24576;
      int kk = r >> 6, o = r & 63;
      int gk = kk >> 6, i = kk & 63;
      float v = tc2w[o * 192 + i * 3 + gk];
      p2ct[o * 128 + (kk >> 5) * 32 + kperm(kk & 31)] = __half_as_ushort(__float2half_rn(v));
    } else if (g < 36864) {                // W2t: k = c_in, col = c_out
      int r = g - 32768;
      int kk = r >> 6, c = r & 63;
      float v = W2[kk * 64 + c];
      W2t[c * 64 + (kk >> 5) * 32 + kperm(kk & 31)] = __half_as_ushort(__float2half_rn(v));
    } else if (g < 36992) {
      int r = g - 36864;
      pb1[r] = tc1b[r & 63];
    }
  }
}

// ---------------- GCN layer 1: fused agg(X) @ W1 + b1, relu ----------------
// h1 FP16 (3.84MB/batch slab -> L2-resident gather). Layout (ushort units):
// [0..128) = interleaved (t0[c],t1[c]) half2 at 2c; [128..192) = t2[c].

__global__ __launch_bounds__(256) void k_aggg1(const float* __restrict__ X,
                                               const float* __restrict__ dinv,
                                               const int* __restrict__ mcnt,
                                               const int* __restrict__ csrc,
                                               const float* __restrict__ cnorm,
                                               const float* __restrict__ W1,
                                               const float* __restrict__ b1,
                                               ushort* __restrict__ h1) {
  int b = blockIdx.x & 7;                    // batch -> XCD affinity
  int grp = blockIdx.x >> 3;                 // 0..2499
  int n = grp * 4 + (threadIdx.x >> 6);
  int lane = threadIdx.x & 63;
  const float2* x0 = (const float2*)(X + (size_t)(b * TT + 9)  * N_NODES * 2);
  const float2* x1 = (const float2*)(X + (size_t)(b * TT + 10) * N_NODES * 2);
  const float2* x2 = (const float2*)(X + (size_t)(b * TT + 11) * N_NODES * 2);
  float a0x = 0.f, a0y = 0.f, a1x = 0.f, a1y = 0.f, a2x = 0.f, a2y = 0.f;
  int m = mcnt[n];
  if (lane < m) {
    int idx = n * CAP + lane;
    float w = cnorm[idx];
    int s = csrc[idx];
    float2 s0 = x0[s], s1 = x1[s], s2v = x2[s];
    a0x = w * s0.x;  a0y = w * s0.y;
    a1x = w * s1.x;  a1y = w * s1.y;
    a2x = w * s2v.x; a2y = w * s2v.y;
  }
  if (lane == 0) {  // self-loop term
    float di = dinv[n];
    float sd = di * di;
    float2 v0 = x0[n], v1 = x1[n], v2 = x2[n];
    a0x += sd * v0.x; a0y += sd * v0.y;
    a1x += sd * v1.x; a1y += sd * v1.y;
    a2x += sd * v2.x; a2y += sd * v2.y;
  }
  #pragma unroll
  for (int off = 32; off > 0; off >>= 1) {
    a0x += __shfl_xor(a0x, off, 64);
    a0y += __shfl_xor(a0y, off, 64);
    a1x += __shfl_xor(a1x, off, 64);
    a1y += __shfl_xor(a1y, off, 64);
    a2x += __shfl_xor(a2x, off, 64);
    a2y += __shfl_xor(a2y, off, 64);
  }
  int c = lane;
  float w0 = W1[c], w1 = W1[64 + c], bc = b1[c];
  float r0 = fmaxf(a0x * w0 + a0y * w1 + bc, 0.0f);
  float r1 = fmaxf(a1x * w0 + a1y * w1 + bc, 0.0f);
  float r2 = fmaxf(a2x * w0 + a2y * w1 + bc, 0.0f);
  ushort* row = h1 + ((size_t)(b * N_NODES + n)) * 192;
  *(__half2*)(row + 2 * c)  = __floats2half2_rn(r0, r1);
  *(__half*)(row + 128 + c) = __float2half_rn(r2);
}

// ---------------- GCN layer 2 aggregation v3: SCALAR metadata, fp16 L2-resident gather ----
// Round-7 structure (1 batch/wave, batch->XCD affinity, 32 waves/CU), but edge metadata
// goes through the SCALAR pipe: n is forced into an SGPR (readfirstlane), so
// csrc[n*CAP+e+u] / cnorm[...] with wave-uniform indices compile to s_load — deleting
// the 2 v_readlane + 2 per-lane metadata loads per edge. Remaining per-edge lane work:
// 2 gather loads + 3 cvt + 3 FMA. Padded slots still have w=0 -> math identical;
// output ah16 fp16 kperm'd as in round 7 (k_fused FROZEN).
__global__ __launch_bounds__(256) void k_agg3m16(const ushort* __restrict__ h1,
                                                 const float* __restrict__ dinv,
                                                 const int* __restrict__ mcnt,
                                                 const int* __restrict__ csrc,
                                                 const float* __restrict__ cnorm,
                                                 ushort* __restrict__ ah16) {
  int b = blockIdx.x & 7;                    // batch -> XCD affinity
  int grp = blockIdx.x >> 3;                 // 0..2499
  int n = __builtin_amdgcn_readfirstlane(grp * 4 + (threadIdx.x >> 6));  // SGPR
  int c = threadIdx.x & 63;
  const ushort* hb = h1 + (size_t)b * N_NODES * 192;
  const int*   se = csrc  + n * CAP;         // SGPR base, scalar-indexed below
  const float* we = cnorm + n * CAP;
  float acc0 = 0.f, acc1 = 0.f, acc2 = 0.f;
  int m = mcnt[n];                           // s_load; <= 64, multiple of 8
  for (int e = 0; e < m; e += 8) {
    #pragma unroll
    for (int u = 0; u < 8; u++) {
      int   off = se[e + u] * 192;           // s_load + s_mul (scalar pipe)
      float w   = we[e + u];                 // s_load
      const ushort* p = hb + off;
      float2 f01 = __half22float2(*(const __half2*)(p + 2 * c));
      float  t2v = __half2float(*(const __half*)(p + 128 + c));
      acc0 += w * f01.x;
      acc1 += w * f01.y;
      acc2 += w * t2v;
    }
  }
  float di = dinv[n];                        // s_load
  float s2 = di * di;
  const ushort* sr = hb + (size_t)n * 192;
  float2 fs = __half22float2(*(const __half2*)(sr + 2 * c));
  float  fst = __half2float(*(const __half*)(sr + 128 + c));
  int oh = ((c >> 5) << 5) + kperm(c & 31);  // kperm'd within-row position
  ushort* orow = ah16 + ((size_t)(b * N_NODES + n)) * 192 + oh;
  *(__half*)&orow[0]   = __float2half_rn(acc0 + s2 * fs.x);   // t3=0 row
  *(__half*)&orow[64]  = __float2half_rn(acc1 + s2 * fs.y);   // t3=1 row
  *(__half*)&orow[128] = __float2half_rn(acc2 + s2 * fst);    // t3=2 row
}

// ---------------- fused epilogue v6 (FROZEN): fp16 MFMA, fp16-kperm'd ah, 4 blocks/CU ----
// Fragment maps (HW-verified rounds 6-7): A elem j <-> k = s*32 + 16*(j>>2) + 4g + (j&3);
// D: col = lane&15, row = 4*(lane>>4) + reg.
__global__ __launch_bounds__(256, 4) void k_fused(const ushort* __restrict__ ah16,
                                                  const ushort* __restrict__ W2t,
                                                  const float* __restrict__ b2,
                                                  const ushort* __restrict__ p1ct,
                                                  const float* __restrict__ pb1,
                                                  const ushort* __restrict__ p2ct,
                                                  const float* __restrict__ tc2b,
                                                  const float* __restrict__ ow,
                                                  const float* __restrict__ obp,
                                                  float* __restrict__ out) {
  __shared__ __align__(16) ushort smem[20480];     // 40,960 B -> 4 blocks/CU
  ushort* spL = smem;                              // [32][192]
  ushort* As  = smem + 6144;                       // [96][64]   (phase 1)
  ushort* W2s = smem + 12288;                      // [64][64]   (phase 1)
  ushort* Wc  = smem + 6144;                       // [128][64] chunk / [64][128] p2c
  ushort* t1L = smem + 16384;                      // [32][128]
  float*  red = (float*)smem;                      // [4][32] floats; overlays dead spL

  int tid = threadIdx.x;
  int lane = tid & 63, w = tid >> 6;
  int l15 = lane & 15, g = lane >> 4;
  size_t nodeBase = (size_t)blockIdx.x * 32;       // in (b*N+n) units
  const ushort* A16 = ah16 + nodeBase * 192;       // 96 rows x 64 halves, kperm'd

  // ---- stage As: straight 16B-chunk copy, XOR bank-swizzle on the LDS side
  #pragma unroll
  for (int rep = 0; rep < 3; rep++) {
    int idx = rep * 256 + tid;                     // 768 chunks of 8 halves
    int m = idx >> 3, j = idx & 7;
    *(uint4*)&As[m * 64 + ((j ^ (m & 7)) << 3)] = *(const uint4*)&A16[m * 64 + (j << 3)];
  }
  // ---- stage W2s (already fp16+permuted in global; add swizzle)
  #pragma unroll
  for (int r = 0; r < 2; r++) {
    int u = r * 256 + tid;                         // 512 x 8 halves
    int cl = u >> 3, hu = u & 7;
    *(uint4*)&W2s[cl * 64 + ((hu * 8) ^ ((cl & 7) << 3))] =
        *(const uint4*)&W2t[cl * 64 + hu * 8];
  }
  __syncthreads();

  // ---- phase 1: sp = relu(As[96x64] @ W2[64x64] + b2); wave w = cols 16w..16w+15
  {
    int col = w * 16 + l15;
    float bias = b2[col];
    f32x4 acc[6];
    #pragma unroll
    for (int i = 0; i < 6; i++) acc[i] = (f32x4){0.f, 0.f, 0.f, 0.f};
    #pragma unroll
    for (int s = 0; s < 2; s++) {
      int oh = s * 32 + 8 * g;
      f16x8 bf = *(const f16x8*)&W2s[col * 64 + (oh ^ ((col & 7) << 3))];
      #pragma unroll
      for (int mi = 0; mi < 6; mi++) {
        int row = mi * 16 + l15;
        f16x8 af = *(const f16x8*)&As[row * 64 + (oh ^ ((row & 7) << 3))];
        acc[mi] = __builtin_amdgcn_mfma_f32_16x16x32_f16(af, bf, acc[mi], 0, 0, 0);
      }
    }
    // epilogue: D row m=(3n+t3) col c -> spL A-layout row n, k = t3*64+c (perm+swz)
    #pragma unroll
    for (int mi = 0; mi < 6; mi++) {
      #pragma unroll
      for (int r = 0; r < 4; r++) {
        int m = mi * 16 + 4 * g + r;
        int n = m / 3, t3 = m - 3 * n;
        float v = fmaxf(acc[mi][r] + bias, 0.0f);
        int k = t3 * 64 + col;
        int oh = (k >> 5) * 32 + kperm(k & 31);
        *(_Float16*)&spL[n * 192 + (oh ^ ((n & 7) << 3))] = (_Float16)v;
      }
    }
  }
  __syncthreads();                                 // As/W2s dead; spL ready

  // ---- phase 2: t1 = relu(spL[32x192] @ p1c[192x128] + pb1); 3 K-chunks of 64
  f32x4 acc2[2][2];
  #pragma unroll
  for (int i = 0; i < 2; i++)
    #pragma unroll
    for (int j = 0; j < 2; j++) acc2[i][j] = (f32x4){0.f, 0.f, 0.f, 0.f};
  int c0 = 32 * w + l15, c1 = c0 + 16;             // wave w cols {32w..+15, 32w+16..+31}
  for (int cc = 0; cc < 3; cc++) {
    #pragma unroll
    for (int r = 0; r < 4; r++) {                  // stage [128 col][64 k] chunk
      int u = r * 256 + tid;
      int cl = u >> 3, hu = u & 7;
      *(uint4*)&Wc[cl * 64 + ((hu * 8) ^ ((cl & 7) << 3))] =
          *(const uint4*)&p1ct[cl * 192 + cc * 64 + hu * 8];
    }
    __syncthreads();
    #pragma unroll
    for (int ks = 0; ks < 2; ks++) {
      int ohB = ks * 32 + 8 * g;
      f16x8 bf0 = *(const f16x8*)&Wc[c0 * 64 + (ohB ^ ((c0 & 7) << 3))];
      f16x8 bf1 = *(const f16x8*)&Wc[c1 * 64 + (ohB ^ ((c1 & 7) << 3))];
      int ohA = (cc * 2 + ks) * 32 + 8 * g;
      #pragma unroll
      for (int mi = 0; mi < 2; mi++) {
        int row = mi * 16 + l15;
        f16x8 af = *(const f16x8*)&spL[row * 192 + (ohA ^ ((row & 7) << 3))];
        acc2[mi][0] = __builtin_amdgcn_mfma_f32_16x16x32_f16(af, bf0, acc2[mi][0], 0, 0, 0);
        acc2[mi][1] = __builtin_amdgcn_mfma_f32_16x16x32_f16(af, bf1, acc2[mi][1], 0, 0, 0);
      }
    }
    __syncthreads();
  }
  // epilogue: t1L A-layout row n, k = col (perm+swz)
  {
    float bz0 = pb1[c0], bz1 = pb1[c1];
    int oh0 = (c0 >> 5) * 32 + kperm(c0 & 31);
    int oh1 = (c1 >> 5) * 32 + kperm(c1 & 31);
    #pragma unroll
    for (int mi = 0; mi < 2; mi++) {
      #pragma unroll
      for (int r = 0; r < 4; r++) {
        int n = mi * 16 + 4 * g + r;
        float v0 = fmaxf(acc2[mi][0][r] + bz0, 0.0f);
        float v1 = fmaxf(acc2[mi][1][r] + bz1, 0.0f);
        *(_Float16*)&t1L[n * 128 + (oh0 ^ ((n & 7) << 3))] = (_Float16)v0;
        *(_Float16*)&t1L[n * 128 + (oh1 ^ ((n & 7) << 3))] = (_Float16)v1;
      }
    }
  }
  // ---- stage p2cs [64 col][128 k] into Wc (t1L and Wc disjoint; one barrier)
  #pragma unroll
  for (int r = 0; r < 4; r++) {
    int u = r * 256 + tid;                         // 1024 x 8 halves
    int cl = u >> 4, hu = u & 15;
    *(uint4*)&Wc[cl * 128 + ((hu * 8) ^ ((cl & 7) << 3))] =
        *(const uint4*)&p2ct[cl * 128 + hu * 8];
  }
  __syncthreads();

  // ---- phase 3: last = relu(t1L[32x128] @ p2c[128x64] + tc2b); dot with ow
  {
    int col = 16 * w + l15;
    f32x4 acc3[2];
    acc3[0] = (f32x4){0.f, 0.f, 0.f, 0.f};
    acc3[1] = (f32x4){0.f, 0.f, 0.f, 0.f};
    #pragma unroll
    for (int s = 0; s < 4; s++) {
      int oh = s * 32 + 8 * g;
      f16x8 bf = *(const f16x8*)&Wc[col * 128 + (oh ^ ((col & 7) << 3))];
      #pragma unroll
      for (int mi = 0; mi < 2; mi++) {
        int row = mi * 16 + l15;
        f16x8 af = *(const f16x8*)&t1L[row * 128 + (oh ^ ((row & 7) << 3))];
        acc3[mi] = __builtin_amdgcn_mfma_f32_16x16x32_f16(af, bf, acc3[mi], 0, 0, 0);
      }
    }
    float tb = tc2b[col], o4 = ow[col];
    float s4[2][4];
    #pragma unroll
    for (int mi = 0; mi < 2; mi++)
      #pragma unroll
      for (int r = 0; r < 4; r++)
        s4[mi][r] = fmaxf(acc3[mi][r] + tb, 0.0f) * o4;
    #pragma unroll
    for (int off = 1; off <= 8; off <<= 1) {
      #pragma unroll
      for (int mi = 0; mi < 2; mi++)
        #pragma unroll
        for (int r = 0; r < 4; r++)
          s4[mi][r] += __shfl_xor(s4[mi][r], off, 64);
    }
    if (l15 == 0) {
      #pragma unroll
      for (int mi = 0; mi < 2; mi++) {
        float4 o;
        o.x = s4[mi][0]; o.y = s4[mi][1]; o.z = s4[mi][2]; o.w = s4[mi][3];
        *(float4*)&red[w * 32 + mi * 16 + 4 * g] = o;
      }
    }
  }
  __syncthreads();
  if (tid < 32) {
    float v = red[tid] + red[32 + tid] + red[64 + tid] + red[96 + tid] + obp[0];
    out[nodeBase + tid] = v;
  }
}

// ---------------- launch ----------------

extern "C" void kernel_launch(void* const* d_in, const int* in_sizes, int n_in,
                              void* d_out, int out_size, void* d_ws, size_t ws_size,
                              hipStream_t stream) {
  const float* X    = (const float*)d_in[0];
  const int*   EI   = (const int*)  d_in[1];
  const float* EW   = (const float*)d_in[2];
  const float* W1   = (const float*)d_in[3];
  const float* B1   = (const float*)d_in[4];
  const float* W2   = (const float*)d_in[5];
  const float* B2   = (const float*)d_in[6];
  const float* TC1W = (const float*)d_in[7];
  const float* TC1B = (const float*)d_in[8];
  const float* TC2W = (const float*)d_in[9];
  const float* TC2B = (const float*)d_in[10];
  const float* OW   = (const float*)d_in[11];
  const float* OB   = (const float*)d_in[12];
  float* out = (float*)d_out;

  char* base = (char*)d_ws;
  size_t off = 0;
  auto alloc = [&](size_t bytes) -> char* {
    char* p = base + off;
    off += (bytes + 255) & ~(size_t)255;
    return p;
  };
  float*  dinv  = (float*) alloc(N_NODES * 4);
  int*    cur   = (int*)   alloc(N_NODES * 4);
  int*    mcnt  = (int*)   alloc(N_NODES * 4);
  int*    csrc  = (int*)   alloc((size_t)N_NODES * CAP * 4);
  float*  cnorm = (float*) alloc((size_t)N_NODES * CAP * 4);
  ushort* p1ct  = (ushort*)alloc(128 * 192 * 2);
  ushort* p2ct  = (ushort*)alloc(64 * 128 * 2);
  ushort* W2t   = (ushort*)alloc(64 * 64 * 2);
  float*  pb1   = (float*) alloc(128 * 4);
  const size_t BIG = (size_t)80000 * 192;
  ushort* h1   = (ushort*)alloc(BIG * 2);  // fp16 h1: 3.84 MB/batch slab (L2-resident)
  ushort* ah16 = (ushort*)alloc(BIG * 2);  // fp16 kperm'd ah: 30.7 MB

  hipMemsetAsync(cur, 0, N_NODES * 4, stream);
  k_fillfix<<<625, 256, 0, stream>>>(EI, EW, cur, csrc, cnorm);
  k_degpad<<<2500, 256, 0, stream>>>(cur, csrc, cnorm, dinv, mcnt);
  // wnorm (blocks 0..2499) + fp16 transposed/permuted weight pack (blocks 2500..2644)
  k_wnormpack<<<2645, 256, 0, stream>>>(cur, csrc, dinv, cnorm, TC1W, TC2W, TC1B, W2,
                                        p1ct, p2ct, W2t, pb1);

  // layer 1 (agg + W1 + relu), t=9..11 fused; h1 fp16 packed (t0,t1 half2 | t2)
  k_aggg1<<<20000, 256, 0, stream>>>(X, dinv, mcnt, csrc, cnorm, W1, B1, h1);
  // layer 2 aggregation: scalar-metadata fp16 L2-resident gather; fp16 kperm'd output
  k_agg3m16<<<20000, 256, 0, stream>>>(h1, dinv, mcnt, csrc, cnorm, ah16);
  // fused W2-GEMM + conv1 + conv2 + out: v6 (fp16 ah, 4 blocks/CU) -- FROZEN
  k_fused<<<2500, 256, 0, stream>>>(ah16, W2t, B2, p1ct, pb1, p2ct, TC2B, OW, OB, out);
}